// Round 5
// baseline (351.761 us; speedup 1.0000x reference)
//
#include <hip/hip_runtime.h>
#include <math.h>

// Problem constants
#define B    2
#define CIN  64
#define LIN  8192
#define L    2048
#define D    128
#define DI   256
#define NS   16
#define RK   8
#define NSTREAM 4        // (dir, batch): s = dir*2 + b
#define CH   32          // tokens per chunk/block
#define NCH  (L/CH)      // 64 chunks per stream
#define TOK  (NSTREAM*L) // 8192
#define SZ_D ((size_t)TOK*D)     // 1,048,576 floats
#define SZ_DI ((size_t)TOK*DI)   // 2,097,152 floats
// LDS row strides (ushorts): start-bank pattern (12r+4q)%32 -> conflict-free b128
#define SXM 280
#define SHN 152

typedef short  bfrag __attribute__((ext_vector_type(8)));
typedef float  facc  __attribute__((ext_vector_type(4)));
#define MFMA __builtin_amdgcn_mfma_f32_16x16x32_bf16

__device__ __forceinline__ float sigmoidf_(float x){ return 1.f/(1.f+__expf(-x)); }
__device__ __forceinline__ float siluf_(float x){ return x*sigmoidf_(x); }
__device__ __forceinline__ ushort f2bf(float f){
    unsigned u = __float_as_uint(f);
    u += 0x7fffu + ((u>>16)&1u);
    return (ushort)(u>>16);
}
__device__ __forceinline__ float bf2f(ushort u){ return __uint_as_float(((unsigned)u)<<16); }
__device__ __forceinline__ float softplusf_(float t){
    return (t > 20.f) ? t : __logf(1.f + __expf(t));
}

// ---------------- fused downsample + weight conversion (unchanged, proven)
__global__ void __launch_bounds__(256,1)
k_downcvt(const float* __restrict__ x, const float* __restrict__ convd_w,
          const float* __restrict__ bias,
          const float* __restrict__ ipw, const float* __restrict__ opw,
          const float* __restrict__ xpw,
          float* __restrict__ h, ushort* __restrict__ wall){
    int tid = threadIdx.x;
    if (blockIdx.x >= 128){
        int g = (blockIdx.x - 128)*256 + tid;
        for (int i = g; i < 688128; i += 32768){
            ushort v;
            if (i < 393216)      v = f2bf(ipw[i]);
            else if (i < 589824) v = f2bf(opw[i-393216]);
            else {
                int t = i - 589824;
                int k = t & 255, nr = (t>>8) & 63, jj = t>>14;
                v = (nr < 40) ? f2bf(xpw[((size_t)jj*40 + nr)*256 + k]) : (ushort)0;
            }
            wall[i] = v;
        }
        return;
    }
    __shared__ ushort sxd[64*SXM];
    __shared__ ushort swt[64*SXM];
    int mb = blockIdx.x & 63, nb = blockIdx.x >> 6;
    int m0 = mb*64;
    int b = m0 >> 11;
    int l0 = m0 & 2047;
    for (int idx = tid; idx < 64*64; idx += 256){
        int t = idx & 63, cc = idx >> 6;
        float4 v = *(const float4*)(x + ((size_t)(b*CIN + cc))*LIN + 4*(l0+t));
        ushort4 o; o.x=f2bf(v.x); o.y=f2bf(v.y); o.z=f2bf(v.z); o.w=f2bf(v.w);
        *(ushort4*)&sxd[t*SXM + cc*4] = o;
    }
    for (int idx = tid; idx < 64*64; idx += 256){
        int cl = idx >> 6, kq = idx & 63;
        float4 v = *(const float4*)(convd_w + ((size_t)(nb*64 + cl))*256 + kq*4);
        ushort4 o; o.x=f2bf(v.x); o.y=f2bf(v.y); o.z=f2bf(v.z); o.w=f2bf(v.w);
        *(ushort4*)&swt[cl*SXM + kq*4] = o;
    }
    __syncthreads();
    int w = tid>>6, lane = tid&63, rw = w>>1, cw_ = w&1;
    int q = lane>>4, r = lane&15;
    int n0 = nb*64 + cw_*32;
    facc acc[2][2] = {};
    #pragma unroll
    for (int kb=0; kb<8; ++kb){
        bfrag a0 = *(bfrag*)&sxd[(rw*32 + r)*SXM + kb*32 + q*8];
        bfrag a1 = *(bfrag*)&sxd[(rw*32 + 16 + r)*SXM + kb*32 + q*8];
        bfrag b0 = *(bfrag*)&swt[(cw_*32 + r)*SXM + kb*32 + q*8];
        bfrag b1 = *(bfrag*)&swt[(cw_*32 + 16 + r)*SXM + kb*32 + q*8];
        acc[0][0] = MFMA(a0,b0,acc[0][0],0,0,0);
        acc[0][1] = MFMA(a0,b1,acc[0][1],0,0,0);
        acc[1][0] = MFMA(a1,b0,acc[1][0],0,0,0);
        acc[1][1] = MFMA(a1,b1,acc[1][1],0,0,0);
    }
    #pragma unroll
    for (int im=0; im<2; ++im)
    #pragma unroll
    for (int in=0; in<2; ++in){
        int col = n0 + in*16 + r;
        float bv = bias[col];
        #pragma unroll
        for (int r2=0; r2<4; ++r2){
            int row = m0 + rw*32 + im*16 + q*4 + r2;
            int bb = row >> 11, l = row & 2047;
            float v = siluf_(acc[im][in][r2] + bv);
            h[((size_t)(bb*L + l))*D + col] = v;
            h[((size_t)((2+bb)*L + (L-1-l)))*D + col] = v;
        }
    }
}

// ---------------- k_layer: full mamba layer, one block per 32-token chunk.
// LN -> in_proj -> conv -> x_proj -> scan1 -> publish+lookback -> scan2+gate -> out_proj.
// Cross-chunk scan carry via per-stream decoupled lookback (flags + agent atomics).
// grid 256 (bi = s*64 + c), block 512.
__global__ void __launch_bounds__(512,1)
k_layer(const float* __restrict__ curIn, const float* __restrict__ resIn,
        float* __restrict__ resOut, float* __restrict__ curOut,
        const float* __restrict__ lnw, const float* __restrict__ lnb,
        const ushort* __restrict__ wbi, const ushort* __restrict__ wbx,
        const ushort* __restrict__ wbo,
        const float* __restrict__ cw, const float* __restrict__ cb,
        const float* __restrict__ Wdt, const float* __restrict__ bdt,
        const float* __restrict__ A_log, const float* __restrict__ Dp,
        ushort* __restrict__ zh,
        float* __restrict__ Ap, float* __restrict__ Bp,
        unsigned* __restrict__ fl, int blk, int first){
    // LDS layout (56,864 B):
    //   [0     ,10640)  smHn  35*SHN ushort  (aliased by sg after conv)
    //   [10640 ,30240)  smXm  35*SXM ushort  (aliased by sg after conv)
    //   [30240 ,48160)  smXc  32*SXM ushort
    //   [48160 ,56864)  smDbc 32*68  float
    __shared__ __align__(16) char smem[56864];
    ushort* smHn  = (ushort*)smem;
    ushort* smXm  = (ushort*)(smem + 10640);
    ushort* smXc  = (ushort*)(smem + 30240);
    float*  smDbc = (float*) (smem + 48160);
    ushort* sg    = (ushort*)smem;            // 32*SXM = 17,920B <= 30,240B

    const int tid = threadIdx.x;
    const int bi  = blockIdx.x;
    const int s = bi >> 6, c = bi & 63;
    const int j = (s>>1)*3 + blk;
    const int base_tok = s*L + c*CH;

    // ---- residual + LN (owned 32 tokens; 16 lanes/token) ----
    {
        int t = tid >> 4, g = tid & 15;
        size_t off = (size_t)(base_tok + t)*D + g*8;
        float4 v[2];
        const float4* cp = (const float4*)(curIn + off);
        v[0] = cp[0]; v[1] = cp[1];
        if (!first){
            const float4* rp = (const float4*)(resIn + off);
            #pragma unroll
            for (int i=0;i<2;++i){ float4 rv=rp[i]; v[i].x+=rv.x; v[i].y+=rv.y; v[i].z+=rv.z; v[i].w+=rv.w; }
        }
        {
            float4* ro = (float4*)(resOut + off);
            ro[0] = v[0]; ro[1] = v[1];
        }
        float s1=0.f, s2=0.f;
        #pragma unroll
        for (int i=0;i<2;++i){
            s1 += v[i].x+v[i].y+v[i].z+v[i].w;
            s2 += v[i].x*v[i].x+v[i].y*v[i].y+v[i].z*v[i].z+v[i].w*v[i].w;
        }
        s1 += __shfl_xor(s1,1); s2 += __shfl_xor(s2,1);
        s1 += __shfl_xor(s1,2); s2 += __shfl_xor(s2,2);
        s1 += __shfl_xor(s1,4); s2 += __shfl_xor(s2,4);
        s1 += __shfl_xor(s1,8); s2 += __shfl_xor(s2,8);
        float mean = s1*(1.f/128.f);
        float var  = s2*(1.f/128.f) - mean*mean;
        float rstd = rsqrtf(var + 1e-5f);
        const float4* lwp = (const float4*)(lnw + j*D + g*8);
        const float4* lbp = (const float4*)(lnb + j*D + g*8);
        #pragma unroll
        for (int i=0;i<2;++i){
            float4 lw = lwp[i], lb = lbp[i];
            ushort4 o;
            o.x = f2bf((v[i].x-mean)*rstd*lw.x + lb.x);
            o.y = f2bf((v[i].y-mean)*rstd*lw.y + lb.y);
            o.z = f2bf((v[i].z-mean)*rstd*lw.z + lb.z);
            o.w = f2bf((v[i].w-mean)*rstd*lw.w + lb.w);
            *(ushort4*)&smHn[t*SHN + g*8 + i*4] = o;
        }
    }
    // ---- halo LN (3 tokens, threads 0..47) ----
    if (c > 0 && tid < 48){
        int t = tid >> 4, g = tid & 15;
        size_t off = (size_t)(base_tok - 3 + t)*D + g*8;
        float4 v[2];
        const float4* cp = (const float4*)(curIn + off);
        v[0] = cp[0]; v[1] = cp[1];
        if (!first){
            const float4* rp = (const float4*)(resIn + off);
            #pragma unroll
            for (int i=0;i<2;++i){ float4 rv=rp[i]; v[i].x+=rv.x; v[i].y+=rv.y; v[i].z+=rv.z; v[i].w+=rv.w; }
        }
        float s1=0.f, s2=0.f;
        #pragma unroll
        for (int i=0;i<2;++i){
            s1 += v[i].x+v[i].y+v[i].z+v[i].w;
            s2 += v[i].x*v[i].x+v[i].y*v[i].y+v[i].z*v[i].z+v[i].w*v[i].w;
        }
        s1 += __shfl_xor(s1,1); s2 += __shfl_xor(s2,1);
        s1 += __shfl_xor(s1,2); s2 += __shfl_xor(s2,2);
        s1 += __shfl_xor(s1,4); s2 += __shfl_xor(s2,4);
        s1 += __shfl_xor(s1,8); s2 += __shfl_xor(s2,8);
        float mean = s1*(1.f/128.f);
        float var  = s2*(1.f/128.f) - mean*mean;
        float rstd = rsqrtf(var + 1e-5f);
        const float4* lwp = (const float4*)(lnw + j*D + g*8);
        const float4* lbp = (const float4*)(lnb + j*D + g*8);
        #pragma unroll
        for (int i=0;i<2;++i){
            float4 lw = lwp[i], lb = lbp[i];
            ushort4 o;
            o.x = f2bf((v[i].x-mean)*rstd*lw.x + lb.x);
            o.y = f2bf((v[i].y-mean)*rstd*lw.y + lb.y);
            o.z = f2bf((v[i].z-mean)*rstd*lw.z + lb.z);
            o.w = f2bf((v[i].w-mean)*rstd*lw.w + lb.w);
            *(ushort4*)&smHn[(32+t)*SHN + g*8 + i*4] = o;
        }
    }
    __syncthreads();

    // ---- in_proj GEMM: M=48, N=512, K=128; 8 waves x 64 cols; z -> zh bf16 ----
    {
        int w = tid>>6, lane = tid&63, q = lane>>4, r = lane&15;
        bfrag a[3][4];
        #pragma unroll
        for (int rt=0; rt<3; ++rt)
        #pragma unroll
        for (int kb=0; kb<4; ++kb)
            a[rt][kb] = *(bfrag*)&smHn[(rt*16 + r)*SHN + kb*32 + q*8];
        #pragma unroll
        for (int ct=0; ct<4; ++ct){
            int n0 = w*64 + ct*16;
            const ushort* bp = wbi + ((size_t)j*512 + n0 + r)*128 + q*8;
            facc a0 = {}, a1 = {}, a2 = {};
            #pragma unroll
            for (int kb=0; kb<4; ++kb){
                bfrag bv = *(const bfrag*)(bp + kb*32);
                a0 = MFMA(a[0][kb], bv, a0, 0,0,0);
                a1 = MFMA(a[1][kb], bv, a1, 0,0,0);
                a2 = MFMA(a[2][kb], bv, a2, 0,0,0);
            }
            int colL = n0 + r;
            if (colL < DI){
                #pragma unroll
                for (int r2=0;r2<4;++r2){
                    int rr = q*4 + r2;
                    smXm[rr*SXM + colL]      = f2bf(a0[r2]);
                    smXm[(16+rr)*SXM + colL] = f2bf(a1[r2]);
                    if (rr < 3) smXm[(32+rr)*SXM + colL] = f2bf(a2[r2]);
                }
            } else {
                int cz = colL - DI;
                #pragma unroll
                for (int r2=0;r2<4;++r2){
                    int rr = q*4 + r2;
                    zh[(size_t)(base_tok + rr)*DI + cz]      = f2bf(a0[r2]);
                    zh[(size_t)(base_tok + 16 + rr)*DI + cz] = f2bf(a1[r2]);
                }
            }
        }
    }
    __syncthreads();

    // ---- conv + silu: thread-per-(d, token-half); LDS only ----
    {
        int d = tid & 255, th = tid >> 8;
        const float* w4 = cw + ((size_t)j*DI + d)*4;
        float cw0=w4[0], cw1=w4[1], cw2=w4[2], cw3=w4[3];
        float cbb = cb[j*DI + d];
        float xm1, xm2, xm3;
        if (th == 0){
            xm1 = xm2 = xm3 = 0.f;
            if (c > 0){
                xm3 = bf2f(smXm[32*SXM + d]);
                xm2 = bf2f(smXm[33*SXM + d]);
                xm1 = bf2f(smXm[34*SXM + d]);
            }
        } else {
            xm3 = bf2f(smXm[13*SXM + d]);
            xm2 = bf2f(smXm[14*SXM + d]);
            xm1 = bf2f(smXm[15*SXM + d]);
        }
        int l0 = th*16;
        #pragma unroll 4
        for (int i=0;i<16;++i){
            int l = l0 + i;
            float x0 = bf2f(smXm[l*SXM + d]);
            float v = siluf_(cbb + cw3*x0 + cw2*xm1 + cw1*xm2 + cw0*xm3);
            smXc[l*SXM + d] = f2bf(v);
            xm3 = xm2; xm2 = xm1; xm1 = x0;
        }
    }
    __syncthreads();

    // ---- x_proj GEMM: M=32, N=64(pad40), K=256 (waves 0..3); LDS only ----
    if (tid < 256){
        int w = tid>>6, lane = tid&63, q = lane>>4, r = lane&15;
        facc a0 = {}, a1 = {};
        const ushort* bp = wbx + ((size_t)j*64 + w*16 + r)*256 + q*8;
        #pragma unroll
        for (int kb=0; kb<8; ++kb){
            bfrag av0 = *(bfrag*)&smXc[r*SXM + kb*32 + q*8];
            bfrag av1 = *(bfrag*)&smXc[(16+r)*SXM + kb*32 + q*8];
            bfrag bv  = *(const bfrag*)(bp + kb*32);
            a0 = MFMA(av0, bv, a0, 0,0,0);
            a1 = MFMA(av1, bv, a1, 0,0,0);
        }
        int col = w*16 + r;
        #pragma unroll
        for (int r2=0;r2<4;++r2){
            int rr = q*4 + r2;
            smDbc[rr*68 + col]      = a0[r2];
            smDbc[(16+rr)*68 + col] = a1[r2];
        }
    }
    __syncthreads();

    // ---- per-thread state: (d2, hh) pair mapping ----
    const int d2 = tid >> 1, hh = tid & 1;
    float A8[8], wv[RK];
    {
        const float* ar = A_log + ((size_t)j*DI + d2)*NS + hh*8;
        #pragma unroll
        for (int n=0;n<8;++n) A8[n] = -__expf(ar[n]);
        const float* wr = Wdt + ((size_t)j*DI + d2)*RK;
        #pragma unroll
        for (int r=0;r<RK;++r) wv[r] = wr[r];
    }
    const float bb2 = bdt[j*DI + d2];

    // ---- scan1: local chunk summary ----
    {
        float ap[8], hsv[8];
        #pragma unroll
        for (int n=0;n<8;++n){ ap[n]=1.f; hsv[n]=0.f; }
        #pragma unroll 4
        for (int l=0;l<CH;++l){
            float t = bb2;
            #pragma unroll
            for (int r=0;r<RK;++r) t += smDbc[l*68+r]*wv[r];
            float dtv = softplusf_(t);
            float xv  = bf2f(smXc[l*SXM + d2]);
            float dbx = dtv*xv;
            #pragma unroll
            for (int n=0;n<8;++n){
                float dA = __expf(dtv*A8[n]);
                ap[n] *= dA;
                hsv[n] = dA*hsv[n] + dbx*smDbc[l*68+8+hh*8+n];
            }
        }
        size_t pb = (size_t)bi*4096 + (size_t)d2*16 + hh*8;
        float4 av0, av1, bv0, bv1;
        av0.x=ap[0];av0.y=ap[1];av0.z=ap[2];av0.w=ap[3];
        av1.x=ap[4];av1.y=ap[5];av1.z=ap[6];av1.w=ap[7];
        bv0.x=hsv[0];bv0.y=hsv[1];bv0.z=hsv[2];bv0.w=hsv[3];
        bv1.x=hsv[4];bv1.y=hsv[5];bv1.z=hsv[6];bv1.w=hsv[7];
        *(float4*)&Ap[pb]   = av0; *(float4*)&Ap[pb+4] = av1;
        *(float4*)&Bp[pb]   = bv0; *(float4*)&Bp[pb+4] = bv1;
    }
    __syncthreads();   // drains vmcnt(0): all summary stores in L2
    if (tid == 0){
        __threadfence();   // L2 writeback -> device-visible
        __hip_atomic_store(&fl[bi], 1u, __ATOMIC_RELEASE, __HIP_MEMORY_SCOPE_AGENT);
    }
    // ---- lookback: wave0 waits for all predecessors of this stream ----
    if (tid < 64 && c > 0){
        const unsigned* fp = fl + s*64 + tid;
        bool ok = (tid >= c);
        unsigned guard = 0;
        while (true){
            if (!ok) ok = (__hip_atomic_load(fp, __ATOMIC_ACQUIRE, __HIP_MEMORY_SCOPE_AGENT) != 0);
            if (__all(ok)) break;
            __builtin_amdgcn_s_sleep(2);
            if (++guard > 20000000u) break;   // hang insurance
        }
    }
    __syncthreads();

    // ---- fold carries (ascending chunk order == old k_scanmid order) ----
    float hs[8];
    #pragma unroll
    for (int n=0;n<8;++n) hs[n] = 0.f;
    {
        size_t sb = ((size_t)(s*64))*4096 + (size_t)d2*16 + hh*8;
        int ci = 0;
        for (; ci+4 <= c; ci += 4){
            float4 aa[4][2], bb4[4][2];
            #pragma unroll
            for (int u=0;u<4;++u){
                const float4* av = (const float4*)&Ap[sb + (size_t)(ci+u)*4096];
                const float4* bv = (const float4*)&Bp[sb + (size_t)(ci+u)*4096];
                aa[u][0]=av[0]; aa[u][1]=av[1]; bb4[u][0]=bv[0]; bb4[u][1]=bv[1];
            }
            #pragma unroll
            for (int u=0;u<4;++u){
                hs[0]=aa[u][0].x*hs[0]+bb4[u][0].x; hs[1]=aa[u][0].y*hs[1]+bb4[u][0].y;
                hs[2]=aa[u][0].z*hs[2]+bb4[u][0].z; hs[3]=aa[u][0].w*hs[3]+bb4[u][0].w;
                hs[4]=aa[u][1].x*hs[4]+bb4[u][1].x; hs[5]=aa[u][1].y*hs[5]+bb4[u][1].y;
                hs[6]=aa[u][1].z*hs[6]+bb4[u][1].z; hs[7]=aa[u][1].w*hs[7]+bb4[u][1].w;
            }
        }
        for (; ci < c; ++ci){
            const float4* av = (const float4*)&Ap[sb + (size_t)ci*4096];
            const float4* bv = (const float4*)&Bp[sb + (size_t)ci*4096];
            float4 a0=av[0], a1=av[1], b0=bv[0], b1=bv[1];
            hs[0]=a0.x*hs[0]+b0.x; hs[1]=a0.y*hs[1]+b0.y;
            hs[2]=a0.z*hs[2]+b0.z; hs[3]=a0.w*hs[3]+b0.w;
            hs[4]=a1.x*hs[4]+b1.x; hs[5]=a1.y*hs[5]+b1.y;
            hs[6]=a1.z*hs[6]+b1.z; hs[7]=a1.w*hs[7]+b1.w;
        }
    }

    // ---- scan2 + gate (sg aliases smHn/smXm: dead since conv) ----
    {
        float Dpd = Dp[j*DI + d2];
        #pragma unroll 4
        for (int l=0;l<CH;++l){
            float t = bb2;
            #pragma unroll
            for (int r=0;r<RK;++r) t += smDbc[l*68+r]*wv[r];
            float dtv = softplusf_(t);
            float xv  = bf2f(smXc[l*SXM + d2]);
            float dbx = dtv*xv;
            float p = 0.f;
            #pragma unroll
            for (int n=0;n<8;++n){
                float dA = __expf(dtv*A8[n]);
                hs[n] = dA*hs[n] + dbx*smDbc[l*68+8+hh*8+n];
                p += hs[n]*smDbc[l*68+24+hh*8+n];
            }
            p += __shfl_xor(p, 1);
            if (hh == 0){
                float zv = bf2f(zh[(size_t)(base_tok+l)*DI + d2]);
                sg[l*SXM + d2] = f2bf((p + Dpd*xv)*siluf_(zv));
            }
        }
    }
    __syncthreads();

    // ---- out_proj: M=32, N=128; 8 waves, wave w -> cols [w*16, w*16+16) ----
    {
        int w = tid>>6, lane = tid&63, q = lane>>4, r = lane&15;
        facc acc0 = {}, acc1 = {};
        const ushort* b0p = wbo + ((size_t)j*128 + w*16 + r)*256 + q*8;
        #pragma unroll
        for (int kb=0; kb<8; ++kb){
            bfrag av0 = *(bfrag*)&sg[r*SXM + kb*32 + q*8];
            bfrag av1 = *(bfrag*)&sg[(16+r)*SXM + kb*32 + q*8];
            bfrag bv0 = *(const bfrag*)(b0p + kb*32);
            acc0 = MFMA(av0,bv0,acc0,0,0,0);
            acc1 = MFMA(av1,bv0,acc1,0,0,0);
        }
        int col = w*16 + r;
        #pragma unroll
        for (int r2=0;r2<4;++r2){
            int row0 = base_tok + q*4 + r2;
            curOut[(size_t)row0*D + col]      = acc0[r2];
            curOut[(size_t)(row0+16)*D + col] = acc1[r2];
        }
    }
}

// ---------------- final combine with LDS transpose (coalesced out0 writes)
__global__ void __launch_bounds__(256,1)
k_final(const float* __restrict__ cur, const float* __restrict__ res,
        float* __restrict__ out){
    __shared__ float sf[128*33];
    int b = blockIdx.y, l0 = blockIdx.x*32;
    int tid = threadIdx.x;
    #pragma unroll
    for (int k=0;k<16;++k){
        int idx = tid + k*256;
        int l = l0 + (idx>>7), d = idx&127;
        int tf  = (b*L + l)*D + d;
        int tbk = ((2+b)*L + (L-1-l))*D + d;
        float f = cur[tf] + res[tf] + cur[tbk] + res[tbk];
        sf[d*33 + (l-l0)] = f;
        out[(size_t)2*D*L + tf] = res[tf];
        out[(size_t)2*D*L + (size_t)((2+b)*L + l)*D + d] = res[((2+b)*L + l)*D + d];
    }
    __syncthreads();
    #pragma unroll
    for (int k=0;k<16;++k){
        int idx = tid + k*256;
        int d = idx>>5, li = idx&31;
        out[((size_t)(b*D + d))*L + l0 + li] = sf[d*33 + li];
    }
}

extern "C" void kernel_launch(void* const* d_in, const int* in_sizes, int n_in,
                              void* d_out, int out_size, void* d_ws, size_t ws_size,
                              hipStream_t stream){
    const float* x         = (const float*)d_in[0];
    const float* convd_w   = (const float*)d_in[1];
    const float* convd_b   = (const float*)d_in[2];
    const float* ln_w      = (const float*)d_in[3];
    const float* ln_b      = (const float*)d_in[4];
    const float* in_proj_w = (const float*)d_in[5];
    const float* conv_w    = (const float*)d_in[6];
    const float* conv_b    = (const float*)d_in[7];
    const float* xproj_w   = (const float*)d_in[8];
    const float* dtproj_w  = (const float*)d_in[9];
    const float* dtproj_b  = (const float*)d_in[10];
    const float* A_log     = (const float*)d_in[11];
    const float* Dparam    = (const float*)d_in[12];
    const float* outproj_w = (const float*)d_in[13];

    float* ws = (float*)d_ws;
    float* h     = ws; ws += SZ_D;
    float* res0  = ws; ws += SZ_D;
    float* res1  = ws; ws += SZ_D;
    float* cur0  = ws; ws += SZ_D;
    float* cur1  = ws; ws += SZ_D;
    ushort* zh   = (ushort*)ws; ws += SZ_DI/2;   // bf16
    float* Ap    = ws; ws += SZ_D;               // [chunk][d][16n] summaries
    float* Bp    = ws; ws += SZ_D;
    unsigned* flags = (unsigned*)ws; ws += 768;  // 3 layers x 256 flags
    ushort* wall = (ushort*)ws;
    ushort* wbi  = wall;
    ushort* wbo  = wall + 393216;
    ushort* wbx  = wall + 589824;

    hipMemsetAsync((void*)flags, 0, 3072, stream);
    k_downcvt<<<256, 256, 0, stream>>>(x, convd_w, convd_b, in_proj_w, outproj_w,
                                       xproj_w, h, wall);

    // layer buffers: blk0: h->cur0 (res0); blk1: cur0->cur1 (res1); blk2: cur1->cur0 (res0)
    const float* ci[3] = { h,    cur0, cur1 };
    const float* ri[3] = { h,    res0, res1 };
    float*       ro[3] = { res0, res1, res0 };
    float*       co[3] = { cur0, cur1, cur0 };
    for (int blk = 0; blk < 3; ++blk){
        k_layer<<<NSTREAM*NCH, 512, 0, stream>>>(ci[blk], ri[blk], ro[blk], co[blk],
                                                 ln_w, ln_b, wbi, wbx, wbo,
                                                 conv_w, conv_b, dtproj_w, dtproj_b,
                                                 A_log, Dparam, zh, Ap, Bp,
                                                 flags + blk*256, blk, blk==0);
    }

    k_final<<<dim3(NCH, B), 256, 0, stream>>>(cur0, res0, (float*)d_out);
}

// Round 6
// 274.395 us; speedup vs baseline: 1.2819x; 1.2819x over previous
//
#include <hip/hip_runtime.h>
#include <math.h>

// Problem constants
#define B    2
#define CIN  64
#define LIN  8192
#define L    2048
#define D    128
#define DI   256
#define NS   16
#define RK   8
#define NSTREAM 4        // (dir, batch): s = dir*2 + b
#define CH   16          // tokens per chunk/block (halved: 2 blocks/CU)
#define NCH  (L/CH)      // 128 chunks per stream
#define TOK  (NSTREAM*L) // 8192
#define SZ_D ((size_t)TOK*D)     // 1,048,576 floats
#define SZ_DI ((size_t)TOK*DI)   // 2,097,152 floats
// LDS row strides (ushorts): start-bank pattern (12r+4q)%32 -> conflict-free b128
#define SXM 280
#define SHN 152

typedef short  bfrag __attribute__((ext_vector_type(8)));
typedef float  facc  __attribute__((ext_vector_type(4)));
#define MFMA __builtin_amdgcn_mfma_f32_16x16x32_bf16

__device__ __forceinline__ float sigmoidf_(float x){ return 1.f/(1.f+__expf(-x)); }
__device__ __forceinline__ float siluf_(float x){ return x*sigmoidf_(x); }
__device__ __forceinline__ ushort f2bf(float f){
    unsigned u = __float_as_uint(f);
    u += 0x7fffu + ((u>>16)&1u);
    return (ushort)(u>>16);
}
__device__ __forceinline__ float bf2f(ushort u){ return __uint_as_float(((unsigned)u)<<16); }
__device__ __forceinline__ float softplusf_(float t){
    return (t > 20.f) ? t : __logf(1.f + __expf(t));
}

// ---------------- fused downsample + weight conversion (unchanged, proven)
__global__ void __launch_bounds__(256,1)
k_downcvt(const float* __restrict__ x, const float* __restrict__ convd_w,
          const float* __restrict__ bias,
          const float* __restrict__ ipw, const float* __restrict__ opw,
          const float* __restrict__ xpw,
          float* __restrict__ h, ushort* __restrict__ wall){
    int tid = threadIdx.x;
    if (blockIdx.x >= 128){
        int g = (blockIdx.x - 128)*256 + tid;
        for (int i = g; i < 688128; i += 32768){
            ushort v;
            if (i < 393216)      v = f2bf(ipw[i]);
            else if (i < 589824) v = f2bf(opw[i-393216]);
            else {
                int t = i - 589824;
                int k = t & 255, nr = (t>>8) & 63, jj = t>>14;
                v = (nr < 40) ? f2bf(xpw[((size_t)jj*40 + nr)*256 + k]) : (ushort)0;
            }
            wall[i] = v;
        }
        return;
    }
    __shared__ ushort sxd[64*SXM];
    __shared__ ushort swt[64*SXM];
    int mb = blockIdx.x & 63, nb = blockIdx.x >> 6;
    int m0 = mb*64;
    int b = m0 >> 11;
    int l0 = m0 & 2047;
    for (int idx = tid; idx < 64*64; idx += 256){
        int t = idx & 63, cc = idx >> 6;
        float4 v = *(const float4*)(x + ((size_t)(b*CIN + cc))*LIN + 4*(l0+t));
        ushort4 o; o.x=f2bf(v.x); o.y=f2bf(v.y); o.z=f2bf(v.z); o.w=f2bf(v.w);
        *(ushort4*)&sxd[t*SXM + cc*4] = o;
    }
    for (int idx = tid; idx < 64*64; idx += 256){
        int cl = idx >> 6, kq = idx & 63;
        float4 v = *(const float4*)(convd_w + ((size_t)(nb*64 + cl))*256 + kq*4);
        ushort4 o; o.x=f2bf(v.x); o.y=f2bf(v.y); o.z=f2bf(v.z); o.w=f2bf(v.w);
        *(ushort4*)&swt[cl*SXM + kq*4] = o;
    }
    __syncthreads();
    int w = tid>>6, lane = tid&63, rw = w>>1, cw_ = w&1;
    int q = lane>>4, r = lane&15;
    int n0 = nb*64 + cw_*32;
    facc acc[2][2] = {};
    #pragma unroll
    for (int kb=0; kb<8; ++kb){
        bfrag a0 = *(bfrag*)&sxd[(rw*32 + r)*SXM + kb*32 + q*8];
        bfrag a1 = *(bfrag*)&sxd[(rw*32 + 16 + r)*SXM + kb*32 + q*8];
        bfrag b0 = *(bfrag*)&swt[(cw_*32 + r)*SXM + kb*32 + q*8];
        bfrag b1 = *(bfrag*)&swt[(cw_*32 + 16 + r)*SXM + kb*32 + q*8];
        acc[0][0] = MFMA(a0,b0,acc[0][0],0,0,0);
        acc[0][1] = MFMA(a0,b1,acc[0][1],0,0,0);
        acc[1][0] = MFMA(a1,b0,acc[1][0],0,0,0);
        acc[1][1] = MFMA(a1,b1,acc[1][1],0,0,0);
    }
    #pragma unroll
    for (int im=0; im<2; ++im)
    #pragma unroll
    for (int in=0; in<2; ++in){
        int col = n0 + in*16 + r;
        float bv = bias[col];
        #pragma unroll
        for (int r2=0; r2<4; ++r2){
            int row = m0 + rw*32 + im*16 + q*4 + r2;
            int bb = row >> 11, l = row & 2047;
            float v = siluf_(acc[im][in][r2] + bv);
            h[((size_t)(bb*L + l))*D + col] = v;
            h[((size_t)((2+bb)*L + (L-1-l)))*D + col] = v;
        }
    }
}

// ---------------- k_head: resln + in_proj + conv + x_proj + scan1, per 16-token chunk
// grid 512 (bi = s*NCH + c), block 512; ~34KB LDS -> 2 blocks/CU (16 waves/CU)
__global__ void __launch_bounds__(512,4)
k_head(const float* __restrict__ curIn, const float* __restrict__ resIn,
       float* __restrict__ resOut,
       const float* __restrict__ lnw, const float* __restrict__ lnb,
       const ushort* __restrict__ wbi, const ushort* __restrict__ wbx,
       const float* __restrict__ cw, const float* __restrict__ cb,
       const float* __restrict__ Wdt, const float* __restrict__ bdt,
       const float* __restrict__ A_log,
       ushort* __restrict__ zh, ushort* __restrict__ xch,
       float* __restrict__ dtr, float* __restrict__ Bc, float* __restrict__ Cc,
       float* __restrict__ Aprod, float* __restrict__ Bend, int blk, int first){
    __shared__ ushort smHn[32*SHN];   // LN out: rows 0..15 owned, 16..18 halo (19..31 pad, reads OK)
    __shared__ ushort smXm[19*SXM];   // xm bf16 (rows 16..18 = halo)
    __shared__ ushort smXc[16*SXM];   // conv out bf16
    __shared__ float  smDbc[16*68];   // xproj out
    const int tid = threadIdx.x;
    const int bi = blockIdx.x;
    const int s = bi >> 7, c = bi & 127;
    const int j = (s>>1)*3 + blk;
    const int base_tok = s*L + c*CH;

    // ---- residual + LN (16 tokens; 32 lanes per token, 1 float4 each) ----
    {
        int t = tid >> 5, g = tid & 31;
        size_t off = (size_t)(base_tok + t)*D + g*4;
        float4 v = *(const float4*)(curIn + off);
        if (!first){
            float4 rv = *(const float4*)(resIn + off);
            v.x+=rv.x; v.y+=rv.y; v.z+=rv.z; v.w+=rv.w;
        }
        *(float4*)(resOut + off) = v;
        float s1 = v.x+v.y+v.z+v.w;
        float s2 = v.x*v.x+v.y*v.y+v.z*v.z+v.w*v.w;
        s1 += __shfl_xor(s1,1);  s2 += __shfl_xor(s2,1);
        s1 += __shfl_xor(s1,2);  s2 += __shfl_xor(s2,2);
        s1 += __shfl_xor(s1,4);  s2 += __shfl_xor(s2,4);
        s1 += __shfl_xor(s1,8);  s2 += __shfl_xor(s2,8);
        s1 += __shfl_xor(s1,16); s2 += __shfl_xor(s2,16);
        float mean = s1*(1.f/128.f);
        float var  = s2*(1.f/128.f) - mean*mean;
        float rstd = rsqrtf(var + 1e-5f);
        float4 lw = *(const float4*)(lnw + j*D + g*4);
        float4 lb = *(const float4*)(lnb + j*D + g*4);
        ushort4 o;
        o.x = f2bf((v.x-mean)*rstd*lw.x + lb.x);
        o.y = f2bf((v.y-mean)*rstd*lw.y + lb.y);
        o.z = f2bf((v.z-mean)*rstd*lw.z + lb.z);
        o.w = f2bf((v.w-mean)*rstd*lw.w + lb.w);
        *(ushort4*)&smHn[t*SHN + g*4] = o;
    }
    // ---- halo LN (3 tokens, threads 0..95; no res write) ----
    if (c > 0 && tid < 96){
        int t = tid >> 5, g = tid & 31;
        size_t off = (size_t)(base_tok - 3 + t)*D + g*4;
        float4 v = *(const float4*)(curIn + off);
        if (!first){
            float4 rv = *(const float4*)(resIn + off);
            v.x+=rv.x; v.y+=rv.y; v.z+=rv.z; v.w+=rv.w;
        }
        float s1 = v.x+v.y+v.z+v.w;
        float s2 = v.x*v.x+v.y*v.y+v.z*v.z+v.w*v.w;
        s1 += __shfl_xor(s1,1);  s2 += __shfl_xor(s2,1);
        s1 += __shfl_xor(s1,2);  s2 += __shfl_xor(s2,2);
        s1 += __shfl_xor(s1,4);  s2 += __shfl_xor(s2,4);
        s1 += __shfl_xor(s1,8);  s2 += __shfl_xor(s2,8);
        s1 += __shfl_xor(s1,16); s2 += __shfl_xor(s2,16);
        float mean = s1*(1.f/128.f);
        float var  = s2*(1.f/128.f) - mean*mean;
        float rstd = rsqrtf(var + 1e-5f);
        float4 lw = *(const float4*)(lnw + j*D + g*4);
        float4 lb = *(const float4*)(lnb + j*D + g*4);
        ushort4 o;
        o.x = f2bf((v.x-mean)*rstd*lw.x + lb.x);
        o.y = f2bf((v.y-mean)*rstd*lw.y + lb.y);
        o.z = f2bf((v.z-mean)*rstd*lw.z + lb.z);
        o.w = f2bf((v.w-mean)*rstd*lw.w + lb.w);
        *(ushort4*)&smHn[(16+t)*SHN + g*4] = o;
    }
    __syncthreads();

    // ---- in_proj GEMM: M=32 (rows 16..31 halo tile, 3 valid), N=512, K=128; 8 waves x 64 cols ----
    {
        int w = tid>>6, lane = tid&63, q = lane>>4, r = lane&15;
        bfrag a[2][4];
        #pragma unroll
        for (int rt=0; rt<2; ++rt)
        #pragma unroll
        for (int kb=0; kb<4; ++kb)
            a[rt][kb] = *(bfrag*)&smHn[(rt*16 + r)*SHN + kb*32 + q*8];
        #pragma unroll
        for (int ct=0; ct<4; ++ct){
            int n0 = w*64 + ct*16;
            const ushort* bp = wbi + ((size_t)j*512 + n0 + r)*128 + q*8;
            facc a0 = {}, a1 = {};
            #pragma unroll
            for (int kb=0; kb<4; ++kb){
                bfrag bv = *(const bfrag*)(bp + kb*32);
                a0 = MFMA(a[0][kb], bv, a0, 0,0,0);
                a1 = MFMA(a[1][kb], bv, a1, 0,0,0);
            }
            int colL = n0 + r;
            if (colL < DI){
                #pragma unroll
                for (int r2=0;r2<4;++r2){
                    int rr = q*4 + r2;
                    smXm[rr*SXM + colL] = f2bf(a0[r2]);
                    if (rr < 3) smXm[(16+rr)*SXM + colL] = f2bf(a1[r2]);
                }
            } else {
                int cz = colL - DI;
                #pragma unroll
                for (int r2=0;r2<4;++r2){
                    int rr = q*4 + r2;
                    zh[(size_t)(base_tok + rr)*DI + cz] = f2bf(a0[r2]);
                }
            }
        }
    }
    __syncthreads();

    // ---- conv + silu: thread-per-(d, token-half of 8); bf16 to LDS + global ----
    {
        int d = tid & 255, th = tid >> 8;
        const float* w4 = cw + ((size_t)j*DI + d)*4;
        float cw0=w4[0], cw1=w4[1], cw2=w4[2], cw3=w4[3];
        float cbb = cb[j*DI + d];
        float xm1, xm2, xm3;
        if (th == 0){
            xm1 = xm2 = xm3 = 0.f;
            if (c > 0){
                xm3 = bf2f(smXm[16*SXM + d]);   // token -3
                xm2 = bf2f(smXm[17*SXM + d]);   // token -2
                xm1 = bf2f(smXm[18*SXM + d]);   // token -1
            }
        } else {
            xm3 = bf2f(smXm[5*SXM + d]);
            xm2 = bf2f(smXm[6*SXM + d]);
            xm1 = bf2f(smXm[7*SXM + d]);
        }
        int l0 = th*8;
        #pragma unroll
        for (int i=0;i<8;++i){
            int l = l0 + i;
            float x0 = bf2f(smXm[l*SXM + d]);
            float v = siluf_(cbb + cw3*x0 + cw2*xm1 + cw1*xm2 + cw0*xm3);
            ushort vb = f2bf(v);
            smXc[l*SXM + d] = vb;
            xch[(size_t)(base_tok+l)*DI + d] = vb;
            xm3 = xm2; xm2 = xm1; xm1 = x0;
        }
    }
    __syncthreads();

    // ---- x_proj GEMM: M=16, N=64(pad40), K=256 (waves 0..3) ----
    if (tid < 256){
        int w = tid>>6, lane = tid&63, q = lane>>4, r = lane&15;
        facc a0 = {};
        const ushort* bp = wbx + ((size_t)j*64 + w*16 + r)*256 + q*8;
        #pragma unroll
        for (int kb=0; kb<8; ++kb){
            bfrag av0 = *(bfrag*)&smXc[r*SXM + kb*32 + q*8];
            bfrag bv  = *(const bfrag*)(bp + kb*32);
            a0 = MFMA(av0, bv, a0, 0,0,0);
        }
        int col = w*16 + r;
        #pragma unroll
        for (int r2=0;r2<4;++r2){
            int rr = q*4 + r2;
            smDbc[rr*68 + col] = a0[r2];
            int row0 = base_tok + rr;
            if      (col < 8){  dtr[(size_t)row0*RK + col] = a0[r2]; }
            else if (col < 24){ Bc [(size_t)row0*NS + (col-8)] = a0[r2]; }
            else if (col < 40){ Cc [(size_t)row0*NS + (col-24)] = a0[r2]; }
        }
    }
    __syncthreads();

    // ---- scan1: thread-per-(d, 8-state half); layout [chunk][d][16n] ----
    {
        int d = tid >> 1, hh = tid & 1;
        float A[8], wv[RK];
        const float* ar = A_log + ((size_t)j*DI + d)*NS + hh*8;
        #pragma unroll
        for (int n=0;n<8;++n) A[n] = -__expf(ar[n]);
        const float* wr = Wdt + ((size_t)j*DI + d)*RK;
        #pragma unroll
        for (int r=0;r<RK;++r) wv[r] = wr[r];
        float bb2 = bdt[j*DI + d];
        float ap[8], hs[8];
        #pragma unroll
        for (int n=0;n<8;++n){ ap[n]=1.f; hs[n]=0.f; }
        #pragma unroll 4
        for (int l=0;l<CH;++l){
            float t = bb2;
            #pragma unroll
            for (int r=0;r<RK;++r) t += smDbc[l*68+r]*wv[r];
            float dtv = softplusf_(t);
            float xv  = bf2f(smXc[l*SXM + d]);
            float dbx = dtv*xv;
            #pragma unroll
            for (int n=0;n<8;++n){
                float dA = __expf(dtv*A[n]);
                ap[n] *= dA;
                hs[n] = dA*hs[n] + dbx*smDbc[l*68+8+hh*8+n];
            }
        }
        size_t pb = (size_t)bi*4096 + (size_t)d*16 + hh*8;
        float4 av0, bv0;
        av0.x=ap[0];av0.y=ap[1];av0.z=ap[2];av0.w=ap[3];
        bv0.x=hs[0];bv0.y=hs[1];bv0.z=hs[2];bv0.w=hs[3];
        *(float4*)&Aprod[pb]   = av0;
        *(float4*)&Bend [pb]   = bv0;
        av0.x=ap[4];av0.y=ap[5];av0.z=ap[6];av0.w=ap[7];
        bv0.x=hs[4];bv0.y=hs[5];bv0.z=hs[6];bv0.w=hs[7];
        *(float4*)&Aprod[pb+4] = av0;
        *(float4*)&Bend [pb+4] = bv0;
    }
}

// ---------------- scan mid: fold NCH=128 chunk summaries; Bend becomes carry-in
__global__ void k_scanmid(const float* __restrict__ Aprod, float* __restrict__ Bend){
    int tid = blockIdx.x*128 + threadIdx.x;   // 16384 total
    int s = tid >> 12;
    int nd = tid & 4095;
    size_t base = (size_t)s*NCH*4096 + nd;
    float h = 0.f;
    for (int c0=0; c0<NCH; c0+=16){
        float a[16], b[16];
        #pragma unroll
        for (int i=0;i<16;++i){
            a[i] = Aprod[base + (size_t)(c0+i)*4096];
            b[i] = Bend [base + (size_t)(c0+i)*4096];
        }
        #pragma unroll
        for (int i=0;i<16;++i){
            Bend[base + (size_t)(c0+i)*4096] = h;   // carry INTO chunk c0+i
            h = a[i]*h + b[i];
        }
    }
}

// ---------------- k_tail: scan2 + gate + out_proj (CH=16)
// grid (NCH, NSTREAM) = 512 blocks, block 512; lane-pair (d, 8-state half)
__global__ void __launch_bounds__(512,4)
k_tail(const float* __restrict__ dtr, const ushort* __restrict__ xch,
       const float* __restrict__ Bc, const float* __restrict__ Cc,
       const float* __restrict__ A_log,
       const float* __restrict__ Wdt, const float* __restrict__ bdt,
       const float* __restrict__ h0, const ushort* __restrict__ zh,
       const float* __restrict__ Dp, const ushort* __restrict__ wbo,
       float* __restrict__ cur, int blk){
    int c = blockIdx.x, s = blockIdx.y; int j = (s>>1)*3 + blk;
    int tid = threadIdx.x;
    __shared__ float sB[CH*NS], sC[CH*NS], sdtr[CH*RK];
    __shared__ ushort sg[CH*SXM];
    int base_tok = s*L + c*CH;
    if (tid < 256){
        sB[tid] = Bc[(size_t)base_tok*NS + tid];
        sC[tid] = Cc[(size_t)base_tok*NS + tid];
    }
    if (tid < 128) sdtr[tid] = dtr[(size_t)base_tok*RK + tid];
    int d = tid >> 1, hh = tid & 1;   // lane-pair: partner at lane^1
    float A[8], wv[RK];
    const float* ar = A_log + ((size_t)j*DI + d)*NS + hh*8;
    #pragma unroll
    for (int n=0;n<8;++n) A[n] = -__expf(ar[n]);
    const float* wr = Wdt + ((size_t)j*DI + d)*RK;
    #pragma unroll
    for (int r=0;r<RK;++r) wv[r] = wr[r];
    float bb = bdt[j*DI + d];
    float Dpd = Dp[j*DI + d];
    float hs[8];
    {
        size_t pb = (size_t)(s*NCH + c)*4096 + (size_t)d*16 + hh*8;
        float4 h0v0 = *(const float4*)&h0[pb];
        float4 h0v1 = *(const float4*)&h0[pb+4];
        hs[0]=h0v0.x; hs[1]=h0v0.y; hs[2]=h0v0.z; hs[3]=h0v0.w;
        hs[4]=h0v1.x; hs[5]=h0v1.y; hs[6]=h0v1.z; hs[7]=h0v1.w;
    }
    __syncthreads();
    #pragma unroll 4
    for (int l=0;l<CH;++l){
        float t = bb;
        #pragma unroll
        for (int r=0;r<RK;++r) t += sdtr[l*RK+r]*wv[r];
        float dtv = softplusf_(t);
        float xv  = bf2f(xch[(size_t)(base_tok+l)*DI + d]);
        float dbx = dtv*xv;
        float p = 0.f;
        #pragma unroll
        for (int n=0;n<8;++n){
            float dA = __expf(dtv*A[n]);
            hs[n] = dA*hs[n] + dbx*sB[l*NS+hh*8+n];
            p += hs[n]*sC[l*NS+hh*8+n];
        }
        p += __shfl_xor(p, 1);
        if (hh == 0){
            float zv = bf2f(zh[(size_t)(base_tok+l)*DI + d]);
            sg[l*SXM + d] = f2bf((p + Dpd*xv)*siluf_(zv));
        }
    }
    __syncthreads();
    // out_proj: M=16, N=128; 8 waves, wave w -> cols [w*16, w*16+16)
    int w = tid>>6, lane = tid&63, q = lane>>4, r = lane&15;
    facc acc0 = {};
    const ushort* b0p = wbo + ((size_t)j*128 + w*16 + r)*256 + q*8;
    #pragma unroll
    for (int kb=0; kb<8; ++kb){
        bfrag av0 = *(bfrag*)&sg[r*SXM + kb*32 + q*8];
        bfrag bv0 = *(const bfrag*)(b0p + kb*32);
        acc0 = MFMA(av0,bv0,acc0,0,0,0);
    }
    int col = w*16 + r;
    #pragma unroll
    for (int r2=0;r2<4;++r2){
        int row0 = base_tok + q*4 + r2;
        cur[(size_t)row0*D + col] = acc0[r2];
    }
}

// ---------------- final combine with LDS transpose (coalesced out0 writes)
__global__ void __launch_bounds__(256,1)
k_final(const float* __restrict__ cur, const float* __restrict__ res,
        float* __restrict__ out){
    __shared__ float sf[128*33];
    int b = blockIdx.y, l0 = blockIdx.x*32;
    int tid = threadIdx.x;
    #pragma unroll
    for (int k=0;k<16;++k){
        int idx = tid + k*256;
        int l = l0 + (idx>>7), d = idx&127;
        int tf  = (b*L + l)*D + d;
        int tbk = ((2+b)*L + (L-1-l))*D + d;
        float f = cur[tf] + res[tf] + cur[tbk] + res[tbk];
        sf[d*33 + (l-l0)] = f;
        out[(size_t)2*D*L + tf] = res[tf];
        out[(size_t)2*D*L + (size_t)((2+b)*L + l)*D + d] = res[((2+b)*L + l)*D + d];
    }
    __syncthreads();
    #pragma unroll
    for (int k=0;k<16;++k){
        int idx = tid + k*256;
        int d = idx>>5, li = idx&31;
        out[((size_t)(b*D + d))*L + l0 + li] = sf[d*33 + li];
    }
}

extern "C" void kernel_launch(void* const* d_in, const int* in_sizes, int n_in,
                              void* d_out, int out_size, void* d_ws, size_t ws_size,
                              hipStream_t stream){
    const float* x         = (const float*)d_in[0];
    const float* convd_w   = (const float*)d_in[1];
    const float* convd_b   = (const float*)d_in[2];
    const float* ln_w      = (const float*)d_in[3];
    const float* ln_b      = (const float*)d_in[4];
    const float* in_proj_w = (const float*)d_in[5];
    const float* conv_w    = (const float*)d_in[6];
    const float* conv_b    = (const float*)d_in[7];
    const float* xproj_w   = (const float*)d_in[8];
    const float* dtproj_w  = (const float*)d_in[9];
    const float* dtproj_b  = (const float*)d_in[10];
    const float* A_log     = (const float*)d_in[11];
    const float* Dparam    = (const float*)d_in[12];
    const float* outproj_w = (const float*)d_in[13];

    float* ws = (float*)d_ws;
    float* h     = ws; ws += SZ_D;
    float* res0  = ws; ws += SZ_D;
    float* res1  = ws; ws += SZ_D;
    float* cur   = ws; ws += SZ_D;
    ushort* zh   = (ushort*)ws; ws += SZ_DI/2;   // bf16
    ushort* xch  = (ushort*)ws; ws += SZ_DI/2;   // bf16
    float* Aprod = ws; ws += SZ_DI;  // NSTREAM*NCH*4096 = 2M floats, [chunk][d][16n]
    float* Bend  = ws; ws += SZ_DI;
    float* dtr   = ws; ws += (size_t)TOK*RK;
    float* Bc    = ws; ws += (size_t)TOK*NS;
    float* Cc    = ws; ws += (size_t)TOK*NS;
    ushort* wall = (ushort*)ws;
    ushort* wbi  = wall;
    ushort* wbo  = wall + 393216;
    ushort* wbx  = wall + 589824;

    k_downcvt<<<256, 256, 0, stream>>>(x, convd_w, convd_b, in_proj_w, outproj_w,
                                       xproj_w, h, wall);

    // res ping-pong: blk0 -> res0, blk1 -> res1, blk2 -> res0 (final reads res0)
    float* resin[3]  = { nullptr, res0, res1 };
    float* resout[3] = { res0,    res1, res0 };
    for (int blk = 0; blk < 3; ++blk){
        const float* ci = (blk==0) ? h : cur;
        const float* ri = (blk==0) ? h : resin[blk];
        k_head<<<NSTREAM*NCH, 512, 0, stream>>>(ci, ri, resout[blk], ln_w, ln_b, wbi, wbx,
                                                conv_w, conv_b, dtproj_w, dtproj_b, A_log,
                                                zh, xch, dtr, Bc, Cc, Aprod, Bend, blk, blk==0);
        k_scanmid<<<128, 128, 0, stream>>>(Aprod, Bend);
        k_tail<<<dim3(NCH, NSTREAM), 512, 0, stream>>>(dtr, xch, Bc, Cc, A_log,
                                                       dtproj_w, dtproj_b, Bend, zh,
                                                       Dparam, wbo, cur, blk);
    }

    k_final<<<dim3(L/32, B), 256, 0, stream>>>(cur, res0, (float*)d_out);
}